// Round 1
// baseline (182.246 us; speedup 1.0000x reference)
//
#include <hip/hip_runtime.h>

// ESN final-state. Key insight: |W_res_diag| < 0.95 strictly -> the per-unit
// recurrence s_t = tanh(u_t + d*s_{t-1}) is a contraction with factor <= 0.95.
// Influence of step t on the final state decays as 0.95^(T-t), so starting
// from s=0 at t = T-512 gives truncation error <= 2*0.95^512 ~ 8e-12.
// We therefore compute only the last K_STEPS projections + a short scan.

#define K_STEPS 512
#define TT 8            // timesteps per GEMM block tile
#define RES 1024
#define INP 128

// 2 MB scratch for the (scaled-by-2) projections of the last K_STEPS rows.
// Device global => no dependence on ws_size; rewritten fully every call.
__device__ float g_proj2[K_STEPS * RES];

// proj2[k][i] = 2 * dot(X[t0+k], W_in[i])   (factor 2 folded for tanh chain)
// Block: 256 threads = 256 reservoir units; grid.x = K_STEPS/TT time tiles,
// grid.y = RES/256 unit groups. X tile (TT rows) staged in LDS; each thread
// streams its W_in row as float4 (L2-resident, read once per 8 timesteps).
__global__ __launch_bounds__(256) void proj_kernel(
    const float* __restrict__ X, const float* __restrict__ W, int t0) {
    __shared__ float4 Xs[TT * (INP / 4)];   // 8 rows * 32 float4 = 4 KB
    const int tid = threadIdx.x;
    const int tile_t = blockIdx.x * TT;               // local step base
    const int unit = blockIdx.y * 256 + tid;

    // X rows are contiguous: 8*128 floats = 256 float4, one per thread.
    const float4* Xg = (const float4*)(X + (size_t)(t0 + tile_t) * INP);
    Xs[tid] = Xg[tid];
    __syncthreads();

    const float4* Wr = (const float4*)(W + (size_t)unit * INP);
    float acc[TT];
#pragma unroll
    for (int t = 0; t < TT; ++t) acc[t] = 0.0f;

#pragma unroll 8
    for (int j = 0; j < INP / 4; ++j) {
        const float4 w = Wr[j];
#pragma unroll
        for (int t = 0; t < TT; ++t) {
            const float4 x = Xs[t * (INP / 4) + j];  // wave-uniform -> broadcast
            acc[t] += w.x * x.x + w.y * x.y + w.z * x.z + w.w * x.w;
        }
    }

#pragma unroll
    for (int t = 0; t < TT; ++t)
        g_proj2[(size_t)(tile_t + t) * RES + unit] = 2.0f * acc[t];
}

// One thread per reservoir unit; 512-step latency-bound tanh chain.
// tanh(z) = 1 - 2/(exp(2z)+1); 2z = proj2[k] + (2d)*s.
__global__ __launch_bounds__(64) void scan_kernel(
    const float* __restrict__ d, float* __restrict__ out, int nsteps) {
    const int i = blockIdx.x * 64 + threadIdx.x;
    const float di2 = 2.0f * d[i];
    float s = 0.0f;
    const float* p = g_proj2 + i;
#pragma unroll 8
    for (int k = 0; k < nsteps; ++k) {
        const float z2 = p[(size_t)k * RES] + di2 * s;     // = 2*(u + d*s)
        const float e = __expf(z2);                        // v_exp_f32 path
        const float r = __builtin_amdgcn_rcpf(e + 1.0f);   // raw v_rcp_f32
        s = 1.0f - 2.0f * r;                               // tanh(z)
    }
    out[i] = s;
}

extern "C" void kernel_launch(void* const* d_in, const int* in_sizes, int n_in,
                              void* d_out, int out_size, void* d_ws, size_t ws_size,
                              hipStream_t stream) {
    const float* X = (const float*)d_in[0];        // [T, 128]
    const float* W_in = (const float*)d_in[1];     // [1024, 128]
    const float* W_diag = (const float*)d_in[2];   // [1024]
    float* out = (float*)d_out;                    // [1024]

    const int T = in_sizes[0] / INP;               // 200000
    const int nsteps = (T < K_STEPS) ? T : K_STEPS;
    const int t0 = T - nsteps;

    dim3 pgrid(nsteps / TT, RES / 256);
    proj_kernel<<<pgrid, 256, 0, stream>>>(X, W_in, t0);
    scan_kernel<<<RES / 64, 64, 0, stream>>>(W_diag, out, nsteps);
}

// Round 2
// 157.078 us; speedup vs baseline: 1.1602x; 1.1602x over previous
//
#include <hip/hip_runtime.h>

// ESN final-state. |W_res_diag| < 0.95 strictly -> recurrence
// s_t = tanh(u_t + d*s_{t-1}) is a per-unit contraction (factor <= 0.95).
// Starting from s=0 at t = T-256 gives truncation error <= 0.95^256 ~ 2e-6,
// vastly below the 2e-2 threshold. So: tiny 256x1024x128 GEMM + 256-step scan.
//
// Scan chain trick: tanh(z) = 1 - 2/(exp2(c*z)+1) with c = 2*log2(e).
// We store proj' = c * dot(x, w) and use d' = c * d, so the per-step
// dependency chain is fma -> exp2 -> add -> rcp -> fma (no ln2 mul).

#define K_STEPS 256
#define TT 8            // timesteps per GEMM block tile
#define RES 1024
#define INP 128
#define C2LOG2E 2.885390081777927f   // 2*log2(e)

// 1 MB scratch for scaled projections of the last K_STEPS rows.
// Device global => no dependence on ws_size; fully rewritten every call.
__device__ float g_proj[K_STEPS * RES];

// proj'[k][i] = C2LOG2E * dot(X[t0+k], W_in[i])
// Block: 256 threads = 256 reservoir units; grid.x = time tiles,
// grid.y = unit groups. X tile (TT rows) staged in LDS (wave-uniform
// broadcast reads); each thread streams its W_in row as float4 (L2-resident).
__global__ __launch_bounds__(256) void proj_kernel(
    const float* __restrict__ X, const float* __restrict__ W, int t0) {
    __shared__ float4 Xs[TT * (INP / 4)];   // 8 rows * 32 float4 = 4 KB
    const int tid = threadIdx.x;
    const int tile_t = blockIdx.x * TT;
    const int unit = blockIdx.y * 256 + tid;

    // 8 contiguous X rows = 256 float4, one per thread.
    const float4* Xg = (const float4*)(X + (size_t)(t0 + tile_t) * INP);
    Xs[tid] = Xg[tid];
    __syncthreads();

    const float4* Wr = (const float4*)(W + (size_t)unit * INP);
    float acc[TT];
#pragma unroll
    for (int t = 0; t < TT; ++t) acc[t] = 0.0f;

#pragma unroll 8
    for (int j = 0; j < INP / 4; ++j) {
        const float4 w = Wr[j];
#pragma unroll
        for (int t = 0; t < TT; ++t) {
            const float4 x = Xs[t * (INP / 4) + j];  // wave-uniform broadcast
            acc[t] += w.x * x.x + w.y * x.y + w.z * x.z + w.w * x.w;
        }
    }

#pragma unroll
    for (int t = 0; t < TT; ++t)
        g_proj[(size_t)(tile_t + t) * RES + unit] = C2LOG2E * acc[t];
}

// One thread per reservoir unit; K_STEPS latency-bound chain.
// s = 1 - 2/(exp2(p' + d'*s) + 1). Loads are chain-independent -> unroll 8
// lets the compiler hoist them ahead (coalesced 256 B/wave/step).
__global__ __launch_bounds__(64) void scan_kernel(
    const float* __restrict__ d, float* __restrict__ out, int nsteps) {
    const int i = blockIdx.x * 64 + threadIdx.x;
    const float dc = C2LOG2E * d[i];
    float s = 0.0f;
    const float* p = g_proj + i;
#pragma unroll 8
    for (int k = 0; k < nsteps; ++k) {
        const float z = p[(size_t)k * RES] + dc * s;      // v_fma
        const float e = __builtin_amdgcn_exp2f(z);        // v_exp_f32 (2^x)
        const float r = __builtin_amdgcn_rcpf(e + 1.0f);  // v_add + v_rcp
        s = __builtin_fmaf(-2.0f, r, 1.0f);               // v_fma
    }
    out[i] = s;
}

extern "C" void kernel_launch(void* const* d_in, const int* in_sizes, int n_in,
                              void* d_out, int out_size, void* d_ws, size_t ws_size,
                              hipStream_t stream) {
    const float* X = (const float*)d_in[0];        // [T, 128]
    const float* W_in = (const float*)d_in[1];     // [1024, 128]
    const float* W_diag = (const float*)d_in[2];   // [1024]
    float* out = (float*)d_out;                    // [1024]

    const int T = in_sizes[0] / INP;               // 200000
    const int nsteps = (T < K_STEPS) ? T : K_STEPS;
    const int t0 = T - nsteps;

    dim3 pgrid(nsteps / TT, RES / 256);
    proj_kernel<<<pgrid, 256, 0, stream>>>(X, W_in, t0);
    scan_kernel<<<RES / 64, 64, 0, stream>>>(W_diag, out, nsteps);
}